// Round 13
// baseline (243.058 us; speedup 1.0000x reference)
//
#include <hip/hip_runtime.h>

#define NF_   2
#define NLOC_ 2048
#define NALL_ 3072
#define NNEI_ 128
#define H_    8
#define D_    32
#define CH_   256   // H*D == Q_DIM

typedef __attribute__((ext_vector_type(8))) short  short8v;   // mfma bf16x8 operand
typedef __attribute__((ext_vector_type(8))) unsigned short ushort8v;
typedef __attribute__((ext_vector_type(4))) float  floatx4;   // mfma f32x4 acc

// fp32 -> bf16 RNE, and back
__device__ __forceinline__ unsigned short f2bf(float x) {
  unsigned u = __float_as_uint(x);
  unsigned r = u + 0x7fff + ((u >> 16) & 1);
  return (unsigned short)(r >> 16);
}
__device__ __forceinline__ float bf2f(unsigned short h) {
  return __uint_as_float(((unsigned)h) << 16);
}

// ---------------------------------------------------------------------------
// One-time W conversion: fp32 [256,256] -> bf16 hi/lo pair (RNE split).
// dst layout: matrix m at dst + m*2*65536; hi then lo, each 65536 ushort.
// ---------------------------------------------------------------------------
__global__ __launch_bounds__(256) void wcvt_kernel(
    const float* __restrict__ W0, const float* __restrict__ W1,
    const float* __restrict__ W2, const float* __restrict__ W3,
    const float* __restrict__ W4, unsigned short* __restrict__ dst) {
  const float* srcs[5] = {W0, W1, W2, W3, W4};
  const float* s = srcs[blockIdx.y];
  unsigned short* hi = dst + (size_t)blockIdx.y * 2 * 65536;
  unsigned short* lo = hi + 65536;
  const int idx = (blockIdx.x * 256 + threadIdx.x) * 4;
  const float4 v = *(const float4*)(s + idx);
  unsigned short h0 = f2bf(v.x), h1 = f2bf(v.y), h2 = f2bf(v.z), h3 = f2bf(v.w);
  ushort4 hv = {h0, h1, h2, h3};
  ushort4 lv = {f2bf(v.x - bf2f(h0)), f2bf(v.y - bf2f(h1)),
                f2bf(v.z - bf2f(h2)), f2bf(v.w - bf2f(h3))};
  *(ushort4*)(hi + idx) = hv;
  *(ushort4*)(lo + idx) = lv;
}

// ---------------------------------------------------------------------------
// One-time activation conversion: q/k/v fp32 -> hi/lo bf16.
// layout in dst: qhi[QN] qlo[QN] khi[KN] klo[KN] vhi[KN] vlo[KN]
// ---------------------------------------------------------------------------
#define QN_ ((size_t)NF_ * NLOC_ * CH_)   // 1,048,576
#define KN_ ((size_t)NF_ * NALL_ * CH_)   // 1,572,864

__global__ __launch_bounds__(256) void acvt_kernel(
    const float* __restrict__ q, const float* __restrict__ k,
    const float* __restrict__ v, unsigned short* __restrict__ dst) {
  const int m = blockIdx.y;
  const float* src;
  unsigned short* hi;
  size_t n;
  if (m == 0)      { src = q; hi = dst;                 n = QN_; }
  else if (m == 1) { src = k; hi = dst + 2 * QN_;       n = KN_; }
  else             { src = v; hi = dst + 2 * QN_ + 2 * KN_; n = KN_; }
  unsigned short* lo = hi + n;
  const size_t idx = ((size_t)blockIdx.x * 256 + threadIdx.x) * 4;
  if (idx >= n) return;
  const float4 val = *(const float4*)(src + idx);
  unsigned short h0 = f2bf(val.x), h1 = f2bf(val.y), h2 = f2bf(val.z), h3 = f2bf(val.w);
  ushort4 hv = {h0, h1, h2, h3};
  ushort4 lv = {f2bf(val.x - bf2f(h0)), f2bf(val.y - bf2f(h1)),
                f2bf(val.z - bf2f(h2)), f2bf(val.w - bf2f(h3))};
  *(ushort4*)(hi + idx) = hv;
  *(ushort4*)(lo + idx) = lv;
}

// ---------------------------------------------------------------------------
// Split-bf16 MFMA GEMM: C[M,256] = A[M,256] @ W[256,256]^T (+ epilogue).
// BOTH operands pre-converted to bf16 hi/lo -> K-loop staging is pure copies
// (6 x 16B global loads, 6 x 16B LDS stores, ZERO VALU between barriers).
// BM=128, BN=64, BK=32, 256 threads = 4 waves (2x2), wave tile 64x32,
// 24 mfma_f32_16x16x32_bf16 per wave per K-step (hi*hi + hi*lo + lo*hi).
// mode: 0 = *norm (qh), 1 = sigmoid(x+bvec) (gate), 2 = none, 3 = +bvec
// ---------------------------------------------------------------------------
__device__ __forceinline__ void gemm_mfma(
    const unsigned short* __restrict__ Ahi, const unsigned short* __restrict__ Alo,
    const unsigned short* __restrict__ Whi, const unsigned short* __restrict__ Wlo,
    const float* __restrict__ bvec, float* __restrict__ C,
    int M, int mode,
    unsigned short (*Ah)[40], unsigned short (*Al)[40],
    unsigned short (*Wh)[40], unsigned short (*Wl)[40]) {
  const int t  = threadIdx.x;
  const int m0 = blockIdx.y * 128;
  if (m0 >= M) return;
  const int n0 = blockIdx.x * 64;

  const int lane = t & 63;
  const int wv   = t >> 6;        // wave 0..3
  const int wr   = wv >> 1;       // wave row 0..1 (M, x64)
  const int wc   = wv & 1;        // wave col 0..1 (N, x32)
  const int l15  = lane & 15;
  const int ko   = (lane >> 4) * 8;   // k-offset of this lane's fragment

  // A staging: thread covers row t>>1 (0..127), 16-ushort half (t&1)*16
  const int sr = t >> 1;
  const int sk = (t & 1) * 16;
  // W staging: thread covers row t>>2 (0..63), 8-ushort col (t&3)*8
  const int wrow = t >> 2;
  const int wk   = (t & 3) * 8;

  floatx4 acc[4][2] = {};

  for (int k0 = 0; k0 < 256; k0 += 32) {
    // pure-copy staging; loads issued before barrier overlap prev MFMAs
    const unsigned short* Aph = Ahi + (size_t)(m0 + sr) * 256 + k0 + sk;
    const unsigned short* Apl = Alo + (size_t)(m0 + sr) * 256 + k0 + sk;
    const ushort8v ah0 = *(const ushort8v*)(Aph);
    const ushort8v ah1 = *(const ushort8v*)(Aph + 8);
    const ushort8v al0 = *(const ushort8v*)(Apl);
    const ushort8v al1 = *(const ushort8v*)(Apl + 8);
    const size_t woff = (size_t)(n0 + wrow) * 256 + k0 + wk;
    const ushort8v whv = *(const ushort8v*)(Whi + woff);
    const ushort8v wlv = *(const ushort8v*)(Wlo + woff);
    __syncthreads();   // previous K-step's LDS reads done
    *(ushort8v*)&Ah[sr][sk + 0] = ah0;
    *(ushort8v*)&Ah[sr][sk + 8] = ah1;
    *(ushort8v*)&Al[sr][sk + 0] = al0;
    *(ushort8v*)&Al[sr][sk + 8] = al1;
    *(ushort8v*)&Wh[wrow][wk] = whv;
    *(ushort8v*)&Wl[wrow][wk] = wlv;
    __syncthreads();   // tile ready

    short8v afh[4], afl[4], bfh[2], bfl[2];
#pragma unroll
    for (int mi = 0; mi < 4; ++mi) {
      const int rr = wr * 64 + mi * 16 + l15;
      afh[mi] = *(const short8v*)&Ah[rr][ko];
      afl[mi] = *(const short8v*)&Al[rr][ko];
    }
#pragma unroll
    for (int ni = 0; ni < 2; ++ni) {
      const int rr = wc * 32 + ni * 16 + l15;
      bfh[ni] = *(const short8v*)&Wh[rr][ko];
      bfl[ni] = *(const short8v*)&Wl[rr][ko];
    }
#pragma unroll
    for (int mi = 0; mi < 4; ++mi)
#pragma unroll
      for (int ni = 0; ni < 2; ++ni) {
        acc[mi][ni] = __builtin_amdgcn_mfma_f32_16x16x32_bf16(
            afh[mi], bfh[ni], acc[mi][ni], 0, 0, 0);
        acc[mi][ni] = __builtin_amdgcn_mfma_f32_16x16x32_bf16(
            afh[mi], bfl[ni], acc[mi][ni], 0, 0, 0);
        acc[mi][ni] = __builtin_amdgcn_mfma_f32_16x16x32_bf16(
            afl[mi], bfh[ni], acc[mi][ni], 0, 0, 0);
      }
  }

  // epilogue: D layout col = lane&15, row = (lane>>4)*4 + r
  const float norm = 0.17677669529663687f;  // 1/sqrt(32)
#pragma unroll
  for (int mi = 0; mi < 4; ++mi)
#pragma unroll
    for (int ni = 0; ni < 2; ++ni) {
      const int col = n0 + wc * 32 + ni * 16 + l15;
      const float bv = (mode == 1 || mode == 3) ? bvec[col] : 0.f;
#pragma unroll
      for (int r = 0; r < 4; ++r) {
        const int row = m0 + wr * 64 + mi * 16 + (lane >> 4) * 4 + r;
        float vv = acc[mi][ni][r];
        if (mode == 0)      vv *= norm;
        else if (mode == 1) vv = 1.f / (1.f + __expf(-(vv + bv)));
        else if (mode == 3) vv += bv;
        C[(size_t)row * 256 + col] = vv;
      }
    }
}

__global__ __launch_bounds__(256, 3) void proj_kernel(
    const unsigned short* __restrict__ ahl, const unsigned short* __restrict__ whl,
    const float* __restrict__ bg,
    float* __restrict__ qh, float* __restrict__ gs,
    float* __restrict__ kh, float* __restrict__ vh) {
  __shared__ unsigned short Ah[128][40], Al[128][40], Wh[64][40], Wl[64][40];
  const unsigned short* Whi = whl + (size_t)blockIdx.z * 2 * 65536;
  const unsigned short* Wlo = Whi + 65536;
  const unsigned short* qhi = ahl;
  const unsigned short* khi = ahl + 2 * QN_;
  const unsigned short* vhi = ahl + 2 * QN_ + 2 * KN_;
  switch (blockIdx.z) {
    case 0:  gemm_mfma(qhi, qhi + QN_, Whi, Wlo, nullptr, qh, NF_ * NLOC_, 0, Ah, Al, Wh, Wl); break;
    case 1:  gemm_mfma(qhi, qhi + QN_, Whi, Wlo, bg,      gs, NF_ * NLOC_, 1, Ah, Al, Wh, Wl); break;
    case 2:  gemm_mfma(khi, khi + KN_, Whi, Wlo, nullptr, kh, NF_ * NALL_, 2, Ah, Al, Wh, Wl); break;
    default: gemm_mfma(vhi, vhi + KN_, Whi, Wlo, nullptr, vh, NF_ * NALL_, 2, Ah, Al, Wh, Wl); break;
  }
}

__global__ __launch_bounds__(256, 3) void out_gemm_kernel(
    const unsigned short* __restrict__ xhl, const unsigned short* __restrict__ whl,
    const float* __restrict__ bo, float* __restrict__ out) {
  __shared__ unsigned short Ah[128][40], Al[128][40], Wh[64][40], Wl[64][40];
  const unsigned short* Whi = whl + (size_t)4 * 2 * 65536;
  const unsigned short* Wlo = Whi + 65536;
  gemm_mfma(xhl, xhl + QN_, Whi, Wlo, bo, out, NF_ * NLOC_, 3, Ah, Al, Wh, Wl);
}

// ---------------------------------------------------------------------------
// Attention: one block per (f, n) atom. 256 threads (4 waves).
// QK: K staged in LDS (XOR-swizzled), unchanged from measured 72us version.
// PV (NEW): 4 waves x 32 neighbors each, float4 V loads (full 1KB row per
// wave instruction), partials reduced via LDS aliased onto dead K_s.
// Output written directly as bf16 hi/lo (feeds pure-copy out_gemm staging).
// ---------------------------------------------------------------------------
__global__ __launch_bounds__(256, 4) void attn_kernel(
    const float* __restrict__ qh, const float* __restrict__ gs,
    const float* __restrict__ kh, const float* __restrict__ vh,
    const void* __restrict__ nlist, const float* __restrict__ bias,
    unsigned short* __restrict__ xhi, unsigned short* __restrict__ xlo) {
  __shared__ float q_s[CH_];
  __shared__ int   jn[NNEI_];
  __shared__ float p[H_][NNEI_ + 4];
  __shared__ float K_s[32][256];   // QK chunk buffer; aliased as red[4][256] in PV

  const int t   = threadIdx.x;
  const int bid = blockIdx.x;        // == f*NLOC + n
  const int f   = bid >> 11;
  const int n   = bid & (NLOC_ - 1);
  const size_t row = (size_t)bid;

  q_s[t] = qh[row * CH_ + t];

  // nlist dtype detection: int64 -> all high 32-bit words are 0
  const int* nl32 = (const int*)nlist;
  int odd_or = 0;
#pragma unroll
  for (int w = 1; w < 16; w += 2) odd_or |= nl32[w];
  if (t < NNEI_) {
    if (odd_or == 0) {
      const long long* nl64 = (const long long*)nlist;
      jn[t] = (int)nl64[row * NNEI_ + t];
    } else {
      jn[t] = nl32[row * NNEI_ + t];
    }
  }
  __syncthreads();

  const int h  = t >> 5;   // head (QK/softmax phase)
  const int il = t & 31;   // lane-in-group
  const int w  = t >> 6;   // wave 0..3
  const int l  = t & 63;   // lane-in-wave

  // q fragment for this head -> registers
  float4 qv[8];
  {
    const float4* qp = (const float4*)(q_s + h * D_);
#pragma unroll
    for (int i = 0; i < 8; ++i) qv[i] = qp[i];
  }

  const float* kbase = kh + (size_t)f * NALL_ * CH_;
  const float* bb    = bias + (((size_t)f * H_ + h) * NLOC_ + n) * NNEI_;

  float s[4];
#pragma unroll
  for (int c = 0; c < 4; ++c) {     // FULL unroll: static local indexing
    if (c) __syncthreads();          // previous chunk's compute done
#pragma unroll
    for (int u = 0; u < 8; ++u) {
      const int r = w * 8 + u;
      const int j = jn[c * 32 + r];
      const float4 kv = *(const float4*)(kbase + (size_t)j * CH_ + l * 4);
      *(float4*)(&K_s[r][(l ^ (r & 7)) * 4]) = kv;
    }
    __syncthreads();                 // chunk ready
    const int swz = il & 7;
    const float4* krow = (const float4*)(&K_s[il][0]);
    float a = 0.f;
#pragma unroll
    for (int d4 = 0; d4 < 8; ++d4) {
      const float4 kv = krow[(h * 8 + d4) ^ swz];
      a = fmaf(qv[d4].x, kv.x, a);
      a = fmaf(qv[d4].y, kv.y, a);
      a = fmaf(qv[d4].z, kv.z, a);
      a = fmaf(qv[d4].w, kv.w, a);
    }
    s[c] = a + bb[c * 32 + il];
  }

  // softmax over 128 values (4 regs x 32 lanes of this head group)
  float m = fmaxf(fmaxf(s[0], s[1]), fmaxf(s[2], s[3]));
#pragma unroll
  for (int off = 16; off >= 1; off >>= 1) m = fmaxf(m, __shfl_xor(m, off));
  float e[4];
  float sum = 0.f;
#pragma unroll
  for (int r = 0; r < 4; ++r) { e[r] = __expf(s[r] - m); sum += e[r]; }
#pragma unroll
  for (int off = 16; off >= 1; off >>= 1) sum += __shfl_xor(sum, off);
  const float inv = 1.f / sum;
#pragma unroll
  for (int r = 0; r < 4; ++r) p[h][il + 32 * r] = e[r] * inv;
  __syncthreads();   // p ready; all waves done with K_s -> alias as red

  // PV: wave g covers neighbors [g*32, g*32+32); lane l: h2=l>>3, d4=l&7
  // computes channels h2*32 + d4*4 .. +3. Full vh row read coalesced (1KB
  // per wave instruction). Partials -> red[g][ch], tree-summed after barrier.
  float* red = (float*)K_s;
  {
    const int g  = w;
    const int h2 = l >> 3;
    const int d4 = l & 7;
    float4 pv4[8];
#pragma unroll
    for (int jj = 0; jj < 8; ++jj)
      pv4[jj] = *(const float4*)(&p[h2][g * 32 + jj * 4]);
    const float* vb2 = vh + (size_t)f * NALL_ * CH_ + h2 * D_ + d4 * 4;
    float4 a4 = {0.f, 0.f, 0.f, 0.f};
#pragma unroll
    for (int jj = 0; jj < 8; ++jj) {
      const int j0 = jn[g * 32 + jj * 4 + 0];
      const int j1 = jn[g * 32 + jj * 4 + 1];
      const int j2 = jn[g * 32 + jj * 4 + 2];
      const int j3 = jn[g * 32 + jj * 4 + 3];
      const float4 v0 = *(const float4*)(vb2 + (size_t)j0 * CH_);
      const float4 v1 = *(const float4*)(vb2 + (size_t)j1 * CH_);
      const float4 v2 = *(const float4*)(vb2 + (size_t)j2 * CH_);
      const float4 v3 = *(const float4*)(vb2 + (size_t)j3 * CH_);
      a4.x = fmaf(pv4[jj].x, v0.x, a4.x); a4.y = fmaf(pv4[jj].x, v0.y, a4.y);
      a4.z = fmaf(pv4[jj].x, v0.z, a4.z); a4.w = fmaf(pv4[jj].x, v0.w, a4.w);
      a4.x = fmaf(pv4[jj].y, v1.x, a4.x); a4.y = fmaf(pv4[jj].y, v1.y, a4.y);
      a4.z = fmaf(pv4[jj].y, v1.z, a4.z); a4.w = fmaf(pv4[jj].y, v1.w, a4.w);
      a4.x = fmaf(pv4[jj].z, v2.x, a4.x); a4.y = fmaf(pv4[jj].z, v2.y, a4.y);
      a4.z = fmaf(pv4[jj].z, v2.z, a4.z); a4.w = fmaf(pv4[jj].z, v2.w, a4.w);
      a4.x = fmaf(pv4[jj].w, v3.x, a4.x); a4.y = fmaf(pv4[jj].w, v3.y, a4.y);
      a4.z = fmaf(pv4[jj].w, v3.z, a4.z); a4.w = fmaf(pv4[jj].w, v3.w, a4.w);
    }
    *(float4*)(&red[g * 256 + h2 * 32 + d4 * 4]) = a4;
  }
  __syncthreads();

  const float gt = gs[row * CH_ + t];
  const float o = (red[t] + red[256 + t]) + (red[512 + t] + red[768 + t]);
  const float xo = gt * o;
  const unsigned short hh = f2bf(xo);
  xhi[row * CH_ + t] = hh;
  xlo[row * CH_ + t] = f2bf(xo - bf2f(hh));
}

// ---------------------------------------------------------------------------
extern "C" void kernel_launch(void* const* d_in, const int* in_sizes, int n_in,
                              void* d_out, int out_size, void* d_ws, size_t ws_size,
                              hipStream_t stream) {
  const float* q     = (const float*)d_in[0];
  const float* k     = (const float*)d_in[1];
  const float* v     = (const float*)d_in[2];
  const void*  nlist = d_in[3];
  const float* bias  = (const float*)d_in[4];
  const float* Wq    = (const float*)d_in[5];
  const float* Wk    = (const float*)d_in[6];
  const float* Wv    = (const float*)d_in[7];
  const float* Wg    = (const float*)d_in[8];
  const float* bg    = (const float*)d_in[9];
  const float* Wo    = (const float*)d_in[10];
  const float* bo    = (const float*)d_in[11];
  float* out = (float*)d_out;

  float* ws = (float*)d_ws;
  float* qh = ws;                                   // [4096,256] f32
  float* gs = qh + QN_;                             // [4096,256] f32
  float* kh = gs + QN_;                             // [6144,256] f32
  float* vh = kh + KN_;                             // [6144,256] f32
  unsigned short* xhl = (unsigned short*)(vh + KN_);  // xhi[QN]+xlo[QN] bf16
  unsigned short* whl = xhl + 2 * QN_;              // [5][2][65536] bf16
  unsigned short* ahl = whl + 5 * 2 * 65536;        // q/k/v hi+lo bf16

  // one-time conversions (independent, memory-bound)
  wcvt_kernel<<<dim3(64, 5), 256, 0, stream>>>(Wq, Wg, Wk, Wv, Wo, whl);
  acvt_kernel<<<dim3(1536, 3), 256, 0, stream>>>(q, k, v, ahl);
  // projections: z = {qh, gate, kh, vh}; 128x64 MFMA tiles, pure-copy staging
  proj_kernel<<<dim3(4, 48, 4), 256, 0, stream>>>(ahl, whl, bg, qh, gs, kh, vh);
  // attention + gating -> x in bf16 hi/lo
  attn_kernel<<<dim3(NF_ * NLOC_), 256, 0, stream>>>(qh, gs, kh, vh, nlist, bias,
                                                     xhl, xhl + QN_);
  // output projection
  out_gemm_kernel<<<dim3(4, 32), 256, 0, stream>>>(xhl, whl, bo, out);
}